// Round 8
// baseline (177.703 us; speedup 1.0000x reference)
//
#include <hip/hip_runtime.h>
#include <hip/hip_bf16.h>
#include <math.h>

typedef __bf16 bf16_t;
typedef __bf16 bf16x8 __attribute__((ext_vector_type(8)));
typedef __bf16 bf16x4 __attribute__((ext_vector_type(4)));
typedef __bf16 bf16x2 __attribute__((ext_vector_type(2)));
typedef float f32x4 __attribute__((ext_vector_type(4)));
typedef unsigned u32x4 __attribute__((ext_vector_type(4)));

// scale 1/sqrt(1024) folded with log2(e), plus half-ulp rounding bias
// (x * 2^0.0028169 = x * (1+2^-9)) so perm-truncation rounds on average.
#define SCALE_L2E 0.045084234f
#define ROUND_B 0.0028169f

#define MFMA16(a, b, c) __builtin_amdgcn_mfma_f32_16x16x32_bf16(a, b, c, 0, 0, 0)

// pack two f32 into bf16x2 (truncate): dst = (hi16(b) << 16) | hi16(a)
__device__ __forceinline__ unsigned pack2(float a, float b) {
  return __builtin_amdgcn_perm(__builtin_bit_cast(unsigned, b),
                               __builtin_bit_cast(unsigned, a), 0x07060302u);
}

// ---------------------------------------------------------------------------
// fused f32 -> bf16 convert of three buffers (x, w_qkv, w_o), 8 elems/thread
// ---------------------------------------------------------------------------
__global__ void convert3_f32_bf16(const float* __restrict__ a, int na,
                                  const float* __restrict__ b, int nb,
                                  const float* __restrict__ c, int nc,
                                  bf16_t* __restrict__ oa, bf16_t* __restrict__ ob,
                                  bf16_t* __restrict__ oc) {
  int i = (blockIdx.x * blockDim.x + threadIdx.x) * 8;
  const float* src;
  bf16_t* dst;
  int off;
  if (i < na) { src = a; dst = oa; off = i; }
  else if (i < na + nb) { src = b; dst = ob; off = i - na; }
  else if (i < na + nb + nc) { src = c; dst = oc; off = i - na - nb; }
  else return;
  float4 u = *(const float4*)&src[off];
  float4 v = *(const float4*)&src[off + 4];
  bf16x8 w = {(bf16_t)u.x, (bf16_t)u.y, (bf16_t)u.z, (bf16_t)u.w,
              (bf16_t)v.x, (bf16_t)v.y, (bf16_t)v.z, (bf16_t)v.w};
  *(bf16x8*)&dst[off] = w;
}

#define GLOBAL_AS __attribute__((address_space(1)))
#define LDS_AS __attribute__((address_space(3)))
__device__ __forceinline__ void g2l16(const void* g, void* l) {
  __builtin_amdgcn_global_load_lds((const GLOBAL_AS void*)g, (LDS_AS void*)l,
                                   16, 0, 0);
}

// ---------------------------------------------------------------------------
// m97-style BT-GEMM, bf16 in: C[m,n] = sum_k A[m,k]*B[n,k] + bias[n]
// GEMM2 uses BN=64 / 512 blocks (2 blocks/CU): R5 measured BN=128 (256
// blocks, 1/CU) at -5.2us — the 2-barrier drain needs a co-resident block
// to overlap with; co-residency >= 2 dominates tile shape here.
// ---------------------------------------------------------------------------
template <typename TC, int BN>
__launch_bounds__(256)
__global__ void gemm_bt_bias(const bf16_t* __restrict__ A,
                             const bf16_t* __restrict__ B,
                             const float* __restrict__ bias,
                             TC* __restrict__ C,
                             int M, int N, int K) {
  constexpr int NT = BN / 32;  // n-frags per wave
  __shared__ bf16_t As[128 * 32];
  __shared__ bf16_t Bs[BN * 32];

  const int t = threadIdx.x;
  const int wave = t >> 6, lane = t & 63, quad = lane >> 4, ln = lane & 15;
  const int wm = (wave >> 1) * 64, wn = (wave & 1) * (BN / 2);
  const int m0 = blockIdx.y * 128, n0 = blockIdx.x * BN;

  const int srow = lane >> 2;
  const int schunk = ((lane & 3) ^ ((lane >> 3) & 3)) * 8;
  const bf16_t* gA0 = &A[(size_t)(m0 + wave * 32 + srow) * K + schunk];
  const bf16_t* gA1 = gA0 + (size_t)16 * K;
  bf16_t* lA0 = &As[(wave * 32) * 32];
  bf16_t* lA1 = &As[(wave * 32 + 16) * 32];
  const bf16_t* gB0 = &B[(size_t)(n0 + (BN == 128 ? wave * 32 : wave * 16) + srow) * K + schunk];
  const bf16_t* gB1 = gB0 + (size_t)16 * K;
  bf16_t* lB0 = &Bs[((BN == 128 ? wave * 32 : wave * 16)) * 32];
  bf16_t* lB1 = &Bs[(wave * 32 + 16) * 32];

  const int cslot = (quad ^ ((ln >> 1) & 3)) * 8;

  f32x4 acc[4][NT];
  for (int i = 0; i < 4; i++)
    for (int j = 0; j < NT; j++) acc[i][j] = (f32x4){0.f, 0.f, 0.f, 0.f};

  for (int k0 = 0; k0 < K; k0 += 32) {
    __syncthreads();
    g2l16(gA0 + k0, lA0);
    g2l16(gA1 + k0, lA1);
    g2l16(gB0 + k0, lB0);
    if (BN == 128) g2l16(gB1 + k0, lB1);
    __syncthreads();

    bf16x8 af[4], bfr[NT];
    for (int mt = 0; mt < 4; mt++)
      af[mt] = *(const bf16x8*)&As[(wm + mt * 16 + ln) * 32 + cslot];
    for (int nt = 0; nt < NT; nt++)
      bfr[nt] = *(const bf16x8*)&Bs[(wn + nt * 16 + ln) * 32 + cslot];
    for (int mt = 0; mt < 4; mt++)
      for (int nt = 0; nt < NT; nt++)
        acc[mt][nt] = MFMA16(af[mt], bfr[nt], acc[mt][nt]);
  }

  for (int nt = 0; nt < NT; nt++) {
    int col = n0 + wn + nt * 16 + ln;
    float bv = bias[col];
    for (int mt = 0; mt < 4; mt++) {
      int row = m0 + wm + mt * 16 + quad * 4;
      for (int r = 0; r < 4; r++)
        C[(size_t)(row + r) * N + col] = (TC)(acc[mt][nt][r] + bv);
    }
  }
}

// ---------------------------------------------------------------------------
// 128x128 BT-GEMM, BK=64 double-buffer, ONE barrier per K-tile (R8).
// R6 counters for the 256^2 kernel: MfmaUtil 20%, VALUBusy 10%, conflicts 0,
// HBM 17% — sync/latency stalls at 192 blocks = 1 block/CU (64 CUs idle).
// This kernel: 256 threads (2x2 waves, 64x64 per wave), 64 KiB LDS ->
// 2 blocks/CU co-resident, grid 24x32 = 768 blocks (all 256 CUs). Cross-
// block wave overlap covers each block's per-tile drain (R5 lesson: co-
// residency >= 2 dominates tile shape; m114 mechanism).
// Staging/read algebra carried verbatim from the refcheck-verified gemm256:
// wave w stages 8 rows/call (rowoff = wave*8 + lane/8), stored k-chunk
// (lane&7) holds logical chunk (lane&7)^(lane>>3); global source pre-applies
// the involution (rule 21); read side: slot = (quad ^ (ln&7)) ^ (4*sk) ->
// logical chunk quad+4*sk of row (wm|wn)*64 + f*16 + ln. 2-way conflicts
// (free). Per tile: 8 staging g2l16 (4KB each), 4x4x2 = 32 MFMA/wave, one
// __syncthreads (vmcnt0+lgkmcnt0+barrier); compiler manages ds_read->MFMA
// waits (m97-verified). No setprio (m190: null on non-phase-split GEMM).
// ---------------------------------------------------------------------------
__launch_bounds__(256, 2)
__global__ void gemm128db(const bf16_t* __restrict__ A,
                          const bf16_t* __restrict__ B,
                          const float* __restrict__ bias,
                          bf16_t* __restrict__ C,
                          int M, int N, int K) {
  __shared__ __align__(16) bf16_t Ab[2][128 * 64];
  __shared__ __align__(16) bf16_t Bb[2][128 * 64];

  const int tid = threadIdx.x;
  const int wave = tid >> 6, lane = tid & 63, quad = lane >> 4, ln = lane & 15;
  const int wm = wave >> 1, wn = wave & 1;  // 2M x 2N
  const int m0 = blockIdx.y * 128, n0 = blockIdx.x * 128;
  const int nt = K >> 6;

  // staging: 4 waves x 8 rows = 32 rows per g2l16 call; 4 calls per matrix.
  const int rowoff = wave * 8 + (lane >> 3);          // 0..31
  const int c8 = ((lane & 7) ^ (lane >> 3)) * 8;      // inverse-swizzled src
  const int w8row = wave * 8;
  const bf16_t* Arow0 = A + (size_t)(m0 + rowoff) * K + c8;
  const bf16_t* Brow0 = B + (size_t)(n0 + rowoff) * K + c8;

  auto stA = [&](int tl) {
    const bf16_t* g = Arow0 + (size_t)tl * 64;
    bf16_t* l = &Ab[tl & 1][w8row * 64];
#pragma unroll
    for (int rr = 0; rr < 128; rr += 32)
      g2l16(g + (size_t)rr * K, l + rr * 64);
  };
  auto stB = [&](int tl) {
    const bf16_t* g = Brow0 + (size_t)tl * 64;
    bf16_t* l = &Bb[tl & 1][w8row * 64];
#pragma unroll
    for (int rr = 0; rr < 128; rr += 32)
      g2l16(g + (size_t)rr * K, l + rr * 64);
  };

  // fragment read addressing (read-side swizzle = same involution)
  const int cswl = (quad ^ (ln & 7)) * 8;
  const int aBase = (wm * 64 + ln) * 64;
  const int bBase = (wn * 64 + ln) * 64;

  f32x4 acc[4][4];
#pragma unroll
  for (int i = 0; i < 4; i++)
#pragma unroll
    for (int j = 0; j < 4; j++) acc[i][j] = (f32x4){0.f, 0.f, 0.f, 0.f};

  bf16x8 af[4][2], bfr[4][2];

  auto ldA = [&](int buf) {
#pragma unroll
    for (int mf = 0; mf < 4; ++mf)
#pragma unroll
      for (int sk = 0; sk < 2; ++sk)
        af[mf][sk] = *(const bf16x8*)&Ab[buf][aBase + mf * 1024 +
                                             (cswl ^ (sk << 5))];
  };
  auto ldB = [&](int buf) {
#pragma unroll
    for (int nf = 0; nf < 4; ++nf)
#pragma unroll
      for (int sk = 0; sk < 2; ++sk)
        bfr[nf][sk] = *(const bf16x8*)&Bb[buf][bBase + nf * 1024 +
                                               (cswl ^ (sk << 5))];
  };
  auto mm = [&]() {
#pragma unroll
    for (int mf = 0; mf < 4; ++mf)
#pragma unroll
      for (int nf = 0; nf < 4; ++nf) {
        f32x4 c = acc[mf][nf];
        c = MFMA16(af[mf][0], bfr[nf][0], c);
        c = MFMA16(af[mf][1], bfr[nf][1], c);
        acc[mf][nf] = c;
      }
  };

  // prologue: stage tile 0 into buf0, drain, go.
  stA(0); stB(0);
  __syncthreads();

  for (int tl = 0; tl < nt; ++tl) {
    const int buf = tl & 1;
    // issue next tile's staging first (HBM latency hides under this tile)
    if (tl + 1 < nt) { stA(tl + 1); stB(tl + 1); }
    // compute tile t from buf; compiler manages lgkmcnt for ds_read->MFMA
    ldA(buf);
    ldB(buf);
    mm();
    // one drain per tile: vmcnt(0)+lgkmcnt(0)+barrier
    __syncthreads();
  }

#pragma unroll
  for (int nf = 0; nf < 4; ++nf) {
    const int col = n0 + wn * 64 + nf * 16 + ln;
    const float bv = bias[col];
#pragma unroll
    for (int mf = 0; mf < 4; ++mf) {
      const int row = m0 + wm * 64 + mf * 16 + quad * 4;
#pragma unroll
      for (int r = 0; r < 4; ++r)
        C[(size_t)(row + r) * N + col] = (bf16_t)(acc[mf][nf][r] + bv);
    }
  }
}

// ---------------------------------------------------------------------------
// Causal attention: MFMA layout chaining, fused-pair K=32 PV, DOUBLE-BUFFERED
// LDS (1 barrier/iter) and PEELED causal phases (mask ops only on the 2
// diagonal iterations). Block = paired q-tiles (p, 31-p): 512 blocks, equal
// work, 2/CU co-resident. Paired = best measured (R3 175.5): each staged K/V
// tile and each kf/vf fragment serves TWO q-sets (R4 unpair was neutral).
// R3 XCD-locality: p in HIGH bits, bh in LOW 5 bits -> same-bh -> same XCD
// (mod 8); 4 bh x 512KB K/V = 2MB < 4MB L2/XCD. T5 setprio on MFMA clusters.
// R6: softmax denominator accumulated as f32x4 per-r partial sums (4
// independent dep chains of depth 4/tile, was one 16-deep serial f32 chain).
// GRID MUST BE 512 (1024 clobbers wob via phantom b=2,3 — R4 failure).
// ---------------------------------------------------------------------------
__launch_bounds__(256, 2)
__global__ void attn_kernel(const bf16_t* __restrict__ qkv,
                            bf16_t* __restrict__ out) {
  constexpr int KP = 72, VP = 72;
  constexpr int BUF = 64 * KP;  // elems per K (or V) buffer
  __shared__ __align__(16) bf16_t KsB[2 * BUF];  // [buf][k][d], swizzled
  __shared__ __align__(16) bf16_t VtB[2 * BUF];  // [buf][d][k], swizzled

  const int t = threadIdx.x;
  const int wave = t >> 6, lane = t & 63, quad = lane >> 4, ln = lane & 15;
  const int p = blockIdx.x >> 5;   // pair: q-tiles p and 31-p (0..15)
  const int bh = blockIdx.x & 31;  // 0..31; same-bh -> same XCD (mod-8)
  const int b = bh >> 4, h = bh & 15;
  const int qA = p * 64, qB = (31 - p) * 64;
  const int ntiles = 32 - p;       // A active for kt <= p; B for all
  const size_t rs = 3072;
  const size_t base = (size_t)b * 2048 * rs;

  // Q as B-operand frags: B[d=quad*8+j][q=ln] = Q[q][d]
  const size_t qoffA = base + (size_t)(qA + wave * 16 + ln) * rs + h * 64;
  const size_t qoffB = base + (size_t)(qB + wave * 16 + ln) * rs + h * 64;
  bf16x8 qfA0 = *(const bf16x8*)&qkv[qoffA + quad * 8];
  bf16x8 qfA1 = *(const bf16x8*)&qkv[qoffA + 32 + quad * 8];
  bf16x8 qfB0 = *(const bf16x8*)&qkv[qoffB + quad * 8];
  bf16x8 qfB1 = *(const bf16x8*)&qkv[qoffB + 32 + quad * 8];

  // O^T accumulators: rows d = ct*16+quad*4+r, col q = ln
  f32x4 oA[4], oB[4];
  f32x4 lAv = (f32x4){0.f, 0.f, 0.f, 0.f};
  f32x4 lBv = (f32x4){0.f, 0.f, 0.f, 0.f};
  for (int ct = 0; ct < 4; ct++) {
    oA[ct] = (f32x4){0.f, 0.f, 0.f, 0.f};
    oB[ct] = (f32x4){0.f, 0.f, 0.f, 0.f};
  }

  // staging maps: K rows r0, r0+32 (b128); V rows 2*r0, 2*r0+1 (b32 pairs)
  const int r0 = t >> 3, c0 = (t & 7) * 8;
  const int ksA = r0 * KP + (((t & 7) + wave) & 7) * 8;  // r0>>3 == wave
  const int ksB2 = (r0 + 32) * KP + (((t & 7) + wave + 4) & 7) * 8;
  const int vkoff = ((((r0 >> 2) + (t & 7)) & 7)) * 8 + 2 * (r0 & 3);

  // running global prefetch pointers (advance by 64 rows per tile)
  const bf16_t* kpa = &qkv[base + 1024 + h * 64 + (size_t)r0 * rs + c0];
  const bf16_t* kpb = kpa + (size_t)32 * rs;
  const bf16_t* vpa = &qkv[base + 2048 + h * 64 + (size_t)(2 * r0) * rs + c0];
  const bf16_t* vpb = vpa + rs;
  const size_t tstep = (size_t)64 * rs;

  // tile 0 into regs
  bf16x8 ka = *(const bf16x8*)kpa; kpa += tstep;
  bf16x8 kb = *(const bf16x8*)kpb; kpb += tstep;
  bf16x8 va2 = *(const bf16x8*)vpa; vpa += tstep;
  bf16x8 vb2 = *(const bf16x8*)vpb; vpb += tstep;

  const int qgA = qA + wave * 16 + ln;  // lane's q (S^T column), set A
  const int qgB = qB + wave * 16 + ln;

  // ---- helpers (forceinline lambdas; bool args are literal at call sites)
  auto stage_to = [&](int buf) {
    bf16_t* KsW = &KsB[buf * BUF];
    bf16_t* VtW = &VtB[buf * BUF];
    *(bf16x8*)&KsW[ksA] = ka;
    *(bf16x8*)&KsW[ksB2] = kb;
#pragma unroll
    for (int j = 0; j < 8; j++) {
      bf16x2 w2 = {va2[j], vb2[j]};
      *(bf16x2*)&VtW[(c0 + j) * VP + vkoff] = w2;
    }
  };
  auto prefetch = [&]() {
    ka = *(const bf16x8*)kpa; kpa += tstep;
    kb = *(const bf16x8*)kpb; kpb += tstep;
    va2 = *(const bf16x8*)vpa; vpa += tstep;
    vb2 = *(const bf16x8*)vpb; vpb += tstep;
  };
  auto load_kfs = [&](const bf16_t* Ks, bf16x8* kf0s, bf16x8* kf1s) {
#pragma unroll
    for (int st = 0; st < 4; st++) {
      const int krow = st * 16 + ln;
      const int rot = 2 * st + (ln >> 3);
      kf0s[st] = *(const bf16x8*)&Ks[krow * KP + ((quad + rot) & 7) * 8];
      kf1s[st] = *(const bf16x8*)&Ks[krow * KP + ((quad + 4 + rot) & 7) * 8];
    }
  };
  auto qk_block = [&](const bf16x8* kf0s, const bf16x8* kf1s, bf16x8 q0,
                      bf16x8 q1, f32x4& lxv, bf16x8* Bp, bool masked,
                      int kbase, int qg) {
#pragma unroll
    for (int pr = 0; pr < 2; pr++) {
      u32x4 u;
#pragma unroll
      for (int sh = 0; sh < 2; sh++) {
        const int st = pr * 2 + sh;
        f32x4 s = (f32x4){0.f, 0.f, 0.f, 0.f};
        __builtin_amdgcn_s_setprio(1);
        s = MFMA16(kf0s[st], q0, s);
        s = MFMA16(kf1s[st], q1, s);
        __builtin_amdgcn_s_setprio(0);
        const int k0g = kbase + st * 16 + quad * 4;
        float pv[4];
#pragma unroll
        for (int r = 0; r < 4; r++) {
          float e = __builtin_amdgcn_exp2f(fmaf(s[r], SCALE_L2E, ROUND_B));
          if (masked && (k0g + r > qg)) e = 0.f;
          lxv[r] += e;  // 4 independent chains (was one 16-deep serial chain)
          pv[r] = e;
        }
        u[sh * 2] = pack2(pv[0], pv[1]);
        u[sh * 2 + 1] = pack2(pv[2], pv[3]);
      }
      Bp[pr] = __builtin_bit_cast(bf16x8, u);
    }
  };
  auto load_vfs = [&](const bf16_t* Vt, bf16x8* A8s) {
#pragma unroll
    for (int pr = 0; pr < 2; pr++) {
#pragma unroll
      for (int ct = 0; ct < 4; ct++) {
        const int dd = ct * 16 + ln;
        const int bc = (quad >> 1) + 2 * ct + (ln >> 3);
        const int cA = (4 * pr + bc) & 7;
        const int cB = (4 * pr + 2 + bc) & 7;
        bf16x4 v0 = *(const bf16x4*)&Vt[dd * VP + cA * 8 + (quad & 1) * 4];
        bf16x4 v1 = *(const bf16x4*)&Vt[dd * VP + cB * 8 + (quad & 1) * 4];
        A8s[pr * 4 + ct] = __builtin_shufflevector(v0, v1, 0, 1, 2, 3, 4, 5, 6, 7);
      }
    }
  };

  // main body for one k-tile. hasA/maskA/maskB are literals at call sites.
  auto body = [&](int kt, bool hasA, bool maskA, bool maskB) {
    // stage next tile into other buffer + issue prefetch of tile kt+2
    if (kt + 1 < ntiles) {
      stage_to((kt + 1) & 1);
      if (kt + 2 < ntiles) prefetch();
    }
    const bf16_t* Ks = &KsB[(kt & 1) * BUF];
    const bf16_t* Vt = &VtB[(kt & 1) * BUF];
    bf16x8 kf0s[4], kf1s[4];
    load_kfs(Ks, kf0s, kf1s);
    bf16x8 BpA[2], BpB[2];
    if (hasA) qk_block(kf0s, kf1s, qfA0, qfA1, lAv, BpA, maskA, kt * 64, qgA);
    qk_block(kf0s, kf1s, qfB0, qfB1, lBv, BpB, maskB, kt * 64, qgB);
    bf16x8 A8s[8];
    load_vfs(Vt, A8s);
    __builtin_amdgcn_s_setprio(1);
#pragma unroll
    for (int pr = 0; pr < 2; pr++) {
#pragma unroll
      for (int ct = 0; ct < 4; ct++) {
        if (hasA) oA[ct] = MFMA16(A8s[pr * 4 + ct], BpA[pr], oA[ct]);
        oB[ct] = MFMA16(A8s[pr * 4 + ct], BpB[pr], oB[ct]);
      }
    }
    __builtin_amdgcn_s_setprio(0);
    if (kt + 1 < ntiles) __syncthreads();
  };

  // prologue: tile 0 into buf0, prefetch tile 1, sync
  stage_to(0);
  if (ntiles > 1) prefetch();
  __syncthreads();

  // peeled phases: [0,p) AB | p A-diag | (p,31-p) B-only | 31-p B-diag
  for (int kt = 0; kt < p; kt++) body(kt, true, false, false);
  body(p, true, true, false);
  for (int kt = p + 1; kt < 31 - p; kt++) body(kt, false, false, false);
  body(31 - p, false, false, true);

  // l: fold f32x4 partials, sum across the 4 quads, normalize+store
  float lAx = (lAv[0] + lAv[1]) + (lAv[2] + lAv[3]);
  float lBx = (lBv[0] + lBv[1]) + (lBv[2] + lBv[3]);
  lAx += __shfl_xor(lAx, 16);
  lAx += __shfl_xor(lAx, 32);
  lBx += __shfl_xor(lBx, 16);
  lBx += __shfl_xor(lBx, 32);
  const float invA = __builtin_amdgcn_rcpf(lAx);
  const float invB = __builtin_amdgcn_rcpf(lBx);
  const int ocol = h * 64 + quad * 4;
#pragma unroll
  for (int ct = 0; ct < 4; ct++) {
    bf16x4 wa, wb;
#pragma unroll
    for (int r = 0; r < 4; r++) {
      wa[r] = (bf16_t)(oA[ct][r] * invA);
      wb[r] = (bf16_t)(oB[ct][r] * invB);
    }
    *(bf16x4*)&out[(size_t)(b * 2048 + qgA) * 1024 + ocol + ct * 16] = wa;
    *(bf16x4*)&out[(size_t)(b * 2048 + qgB) * 1024 + ocol + ct * 16] = wb;
  }
}

extern "C" void kernel_launch(void* const* d_in, const int* in_sizes, int n_in,
                              void* d_out, int out_size, void* d_ws, size_t ws_size,
                              hipStream_t stream) {
  const float* x     = (const float*)d_in[0];  // [2,2048,1024]
  const float* w_qkv = (const float*)d_in[1];  // [3072,1024]
  const float* b_qkv = (const float*)d_in[2];  // [3072]
  const float* w_o   = (const float*)d_in[3];  // [1024,1024]
  const float* b_o   = (const float*)d_in[4];  // [1024]
  float* out = (float*)d_out;                  // [2,2048,1024]

  // workspace (bf16): qkv | xbf/attn (aliased) | wqkv_bf | wo_bf  = 42 MB
  bf16_t* qkv   = (bf16_t*)d_ws;
  bf16_t* xbf   = qkv + (size_t)4096 * 3072;
  bf16_t* wqkvb = xbf + (size_t)4096 * 1024;
  bf16_t* wob   = wqkvb + (size_t)3072 * 1024;
  bf16_t* attn  = xbf;  // x dead after GEMM1

  const int na = 4096 * 1024, nb = 3072 * 1024, nc = 1024 * 1024;
  convert3_f32_bf16<<<dim3((na + nb + nc) / (256 * 8)), 256, 0, stream>>>(
      x, na, w_qkv, nb, w_o, nc, xbf, wqkvb, wob);

  // 1) qkv = x @ w_qkv^T + b_qkv   (128^2 dbuf 1-barrier, 24x32 = 768 blocks,
  //    2 blocks/CU co-resident)
  gemm128db<<<dim3(3072 / 128, 4096 / 128), 256, 0, stream>>>(
      xbf, wqkvb, b_qkv, qkv, 4096, 3072, 1024);
  // 2) causal attention, paired q-tiles (p, 31-p): EXACTLY 512 blocks
  attn_kernel<<<dim3(512), 256, 0, stream>>>(qkv, attn);
  // 3) out = attn @ w_o^T + b_o    (128x64 tiles -> 512 blocks, 2/CU)
  gemm_bt_bias<float, 64><<<dim3(1024 / 64, 4096 / 128), 256, 0, stream>>>(
      attn, wob, b_o, out, 4096, 1024, 1024);
}

// Round 9
// 177.382 us; speedup vs baseline: 1.0018x; 1.0018x over previous
//
#include <hip/hip_runtime.h>
#include <hip/hip_bf16.h>
#include <math.h>

typedef __bf16 bf16_t;
typedef __bf16 bf16x8 __attribute__((ext_vector_type(8)));
typedef __bf16 bf16x4 __attribute__((ext_vector_type(4)));
typedef __bf16 bf16x2 __attribute__((ext_vector_type(2)));
typedef float f32x4 __attribute__((ext_vector_type(4)));
typedef unsigned u32x4 __attribute__((ext_vector_type(4)));

// scale 1/sqrt(1024) folded with log2(e), plus half-ulp rounding bias
// (x * 2^0.0028169 = x * (1+2^-9)) so perm-truncation rounds on average.
#define SCALE_L2E 0.045084234f
#define ROUND_B 0.0028169f

#define MFMA16(a, b, c) __builtin_amdgcn_mfma_f32_16x16x32_bf16(a, b, c, 0, 0, 0)

// pack two f32 into bf16x2 (truncate): dst = (hi16(b) << 16) | hi16(a)
__device__ __forceinline__ unsigned pack2(float a, float b) {
  return __builtin_amdgcn_perm(__builtin_bit_cast(unsigned, b),
                               __builtin_bit_cast(unsigned, a), 0x07060302u);
}

// ---------------------------------------------------------------------------
// fused f32 -> bf16 convert of three buffers (x, w_qkv, w_o), 8 elems/thread
// ---------------------------------------------------------------------------
__global__ void convert3_f32_bf16(const float* __restrict__ a, int na,
                                  const float* __restrict__ b, int nb,
                                  const float* __restrict__ c, int nc,
                                  bf16_t* __restrict__ oa, bf16_t* __restrict__ ob,
                                  bf16_t* __restrict__ oc) {
  int i = (blockIdx.x * blockDim.x + threadIdx.x) * 8;
  const float* src;
  bf16_t* dst;
  int off;
  if (i < na) { src = a; dst = oa; off = i; }
  else if (i < na + nb) { src = b; dst = ob; off = i - na; }
  else if (i < na + nb + nc) { src = c; dst = oc; off = i - na - nb; }
  else return;
  float4 u = *(const float4*)&src[off];
  float4 v = *(const float4*)&src[off + 4];
  bf16x8 w = {(bf16_t)u.x, (bf16_t)u.y, (bf16_t)u.z, (bf16_t)u.w,
              (bf16_t)v.x, (bf16_t)v.y, (bf16_t)v.z, (bf16_t)v.w};
  *(bf16x8*)&dst[off] = w;
}

#define GLOBAL_AS __attribute__((address_space(1)))
#define LDS_AS __attribute__((address_space(3)))
__device__ __forceinline__ void g2l16(const void* g, void* l) {
  __builtin_amdgcn_global_load_lds((const GLOBAL_AS void*)g, (LDS_AS void*)l,
                                   16, 0, 0);
}

// ---------------------------------------------------------------------------
// m97-style BT-GEMM, bf16 in: C[m,n] = sum_k A[m,k]*B[n,k] + bias[n]
// GEMM2 uses BN=64 / 512 blocks (2 blocks/CU): R5 measured BN=128 (256
// blocks, 1/CU) at -5.2us — the 2-barrier drain needs a co-resident block
// to overlap with; co-residency >= 2 dominates tile shape here.
// ---------------------------------------------------------------------------
template <typename TC, int BN>
__launch_bounds__(256)
__global__ void gemm_bt_bias(const bf16_t* __restrict__ A,
                             const bf16_t* __restrict__ B,
                             const float* __restrict__ bias,
                             TC* __restrict__ C,
                             int M, int N, int K) {
  constexpr int NT = BN / 32;  // n-frags per wave
  __shared__ bf16_t As[128 * 32];
  __shared__ bf16_t Bs[BN * 32];

  const int t = threadIdx.x;
  const int wave = t >> 6, lane = t & 63, quad = lane >> 4, ln = lane & 15;
  const int wm = (wave >> 1) * 64, wn = (wave & 1) * (BN / 2);
  const int m0 = blockIdx.y * 128, n0 = blockIdx.x * BN;

  const int srow = lane >> 2;
  const int schunk = ((lane & 3) ^ ((lane >> 3) & 3)) * 8;
  const bf16_t* gA0 = &A[(size_t)(m0 + wave * 32 + srow) * K + schunk];
  const bf16_t* gA1 = gA0 + (size_t)16 * K;
  bf16_t* lA0 = &As[(wave * 32) * 32];
  bf16_t* lA1 = &As[(wave * 32 + 16) * 32];
  const bf16_t* gB0 = &B[(size_t)(n0 + (BN == 128 ? wave * 32 : wave * 16) + srow) * K + schunk];
  const bf16_t* gB1 = gB0 + (size_t)16 * K;
  bf16_t* lB0 = &Bs[((BN == 128 ? wave * 32 : wave * 16)) * 32];
  bf16_t* lB1 = &Bs[(wave * 32 + 16) * 32];

  const int cslot = (quad ^ ((ln >> 1) & 3)) * 8;

  f32x4 acc[4][NT];
  for (int i = 0; i < 4; i++)
    for (int j = 0; j < NT; j++) acc[i][j] = (f32x4){0.f, 0.f, 0.f, 0.f};

  for (int k0 = 0; k0 < K; k0 += 32) {
    __syncthreads();
    g2l16(gA0 + k0, lA0);
    g2l16(gA1 + k0, lA1);
    g2l16(gB0 + k0, lB0);
    if (BN == 128) g2l16(gB1 + k0, lB1);
    __syncthreads();

    bf16x8 af[4], bfr[NT];
    for (int mt = 0; mt < 4; mt++)
      af[mt] = *(const bf16x8*)&As[(wm + mt * 16 + ln) * 32 + cslot];
    for (int nt = 0; nt < NT; nt++)
      bfr[nt] = *(const bf16x8*)&Bs[(wn + nt * 16 + ln) * 32 + cslot];
    for (int mt = 0; mt < 4; mt++)
      for (int nt = 0; nt < NT; nt++)
        acc[mt][nt] = MFMA16(af[mt], bfr[nt], acc[mt][nt]);
  }

  for (int nt = 0; nt < NT; nt++) {
    int col = n0 + wn + nt * 16 + ln;
    float bv = bias[col];
    for (int mt = 0; mt < 4; mt++) {
      int row = m0 + wm + mt * 16 + quad * 4;
      for (int r = 0; r < 4; r++)
        C[(size_t)(row + r) * N + col] = (TC)(acc[mt][nt][r] + bv);
    }
  }
}

// ---------------------------------------------------------------------------
// 128x128 BT-GEMM, BK=64 double-buffer, ONE barrier per K-tile (R8, kept).
// 256 threads (2x2 waves), 64 KiB LDS -> 2 blocks/CU, 768 blocks.
// Staging/read algebra verbatim from the refcheck-verified gemm256 swizzle.
// ---------------------------------------------------------------------------
__launch_bounds__(256, 2)
__global__ void gemm128db(const bf16_t* __restrict__ A,
                          const bf16_t* __restrict__ B,
                          const float* __restrict__ bias,
                          bf16_t* __restrict__ C,
                          int M, int N, int K) {
  __shared__ __align__(16) bf16_t Ab[2][128 * 64];
  __shared__ __align__(16) bf16_t Bb[2][128 * 64];

  const int tid = threadIdx.x;
  const int wave = tid >> 6, lane = tid & 63, quad = lane >> 4, ln = lane & 15;
  const int wm = wave >> 1, wn = wave & 1;  // 2M x 2N
  const int m0 = blockIdx.y * 128, n0 = blockIdx.x * 128;
  const int nt = K >> 6;

  const int rowoff = wave * 8 + (lane >> 3);          // 0..31
  const int c8 = ((lane & 7) ^ (lane >> 3)) * 8;      // inverse-swizzled src
  const int w8row = wave * 8;
  const bf16_t* Arow0 = A + (size_t)(m0 + rowoff) * K + c8;
  const bf16_t* Brow0 = B + (size_t)(n0 + rowoff) * K + c8;

  auto stA = [&](int tl) {
    const bf16_t* g = Arow0 + (size_t)tl * 64;
    bf16_t* l = &Ab[tl & 1][w8row * 64];
#pragma unroll
    for (int rr = 0; rr < 128; rr += 32)
      g2l16(g + (size_t)rr * K, l + rr * 64);
  };
  auto stB = [&](int tl) {
    const bf16_t* g = Brow0 + (size_t)tl * 64;
    bf16_t* l = &Bb[tl & 1][w8row * 64];
#pragma unroll
    for (int rr = 0; rr < 128; rr += 32)
      g2l16(g + (size_t)rr * K, l + rr * 64);
  };

  const int cswl = (quad ^ (ln & 7)) * 8;
  const int aBase = (wm * 64 + ln) * 64;
  const int bBase = (wn * 64 + ln) * 64;

  f32x4 acc[4][4];
#pragma unroll
  for (int i = 0; i < 4; i++)
#pragma unroll
    for (int j = 0; j < 4; j++) acc[i][j] = (f32x4){0.f, 0.f, 0.f, 0.f};

  bf16x8 af[4][2], bfr[4][2];

  auto ldA = [&](int buf) {
#pragma unroll
    for (int mf = 0; mf < 4; ++mf)
#pragma unroll
      for (int sk = 0; sk < 2; ++sk)
        af[mf][sk] = *(const bf16x8*)&Ab[buf][aBase + mf * 1024 +
                                             (cswl ^ (sk << 5))];
  };
  auto ldB = [&](int buf) {
#pragma unroll
    for (int nf = 0; nf < 4; ++nf)
#pragma unroll
      for (int sk = 0; sk < 2; ++sk)
        bfr[nf][sk] = *(const bf16x8*)&Bb[buf][bBase + nf * 1024 +
                                               (cswl ^ (sk << 5))];
  };
  auto mm = [&]() {
#pragma unroll
    for (int mf = 0; mf < 4; ++mf)
#pragma unroll
      for (int nf = 0; nf < 4; ++nf) {
        f32x4 c = acc[mf][nf];
        c = MFMA16(af[mf][0], bfr[nf][0], c);
        c = MFMA16(af[mf][1], bfr[nf][1], c);
        acc[mf][nf] = c;
      }
  };

  stA(0); stB(0);
  __syncthreads();

  for (int tl = 0; tl < nt; ++tl) {
    const int buf = tl & 1;
    if (tl + 1 < nt) { stA(tl + 1); stB(tl + 1); }
    ldA(buf);
    ldB(buf);
    mm();
    __syncthreads();
  }

#pragma unroll
  for (int nf = 0; nf < 4; ++nf) {
    const int col = n0 + wn * 64 + nf * 16 + ln;
    const float bv = bias[col];
#pragma unroll
    for (int mf = 0; mf < 4; ++mf) {
      const int row = m0 + wm * 64 + mf * 16 + quad * 4;
#pragma unroll
      for (int r = 0; r < 4; ++r)
        C[(size_t)(row + r) * N + col] = (bf16_t)(acc[mf][nf][r] + bv);
    }
  }
}

// ---------------------------------------------------------------------------
// Causal attention, K-SPLIT 8-WAVE (R9): paired q-tiles (p,31-p), 512 blocks,
// 512 threads. Wave w = (q-group w&3, k-half w>>2). Same aggregate work as
// the 4-wave version (128 MFMA/tile, same LDS reads/writes) but 2x waves ->
// 4 waves/SIMD (was 2) and per-wave serial chains halved — pure TLP fix for
// the R2-measured latency-boundness (MfmaUtil 15.8, VALU 34, Occ 15%, ~50%
// no-pipe cycles; R4's unpair failed because it DOUBLED LDS work — this
// doesn't). Staging by role: waves 0-3 stage V, waves 4-7 stage K, both with
// the verified 256-thread maps on t&255. Epilogue: cross-half O/l reduction
// through the dead K/V LDS buffers. R3 XCD map (bh in low 5 bits) kept.
// R6 f32x4 l-chains kept. GRID MUST BE 512.
// ---------------------------------------------------------------------------
__launch_bounds__(512, 4)
__global__ void attn_kernel(const bf16_t* __restrict__ qkv,
                            bf16_t* __restrict__ out) {
  constexpr int KP = 72, VP = 72;
  constexpr int BUF = 64 * KP;  // elems per K (or V) buffer
  __shared__ __align__(16) bf16_t KsB[2 * BUF];  // [buf][k][d], swizzled
  __shared__ __align__(16) bf16_t VtB[2 * BUF];  // [buf][d][k], swizzled

  const int t = threadIdx.x;
  const int wave = t >> 6, lane = t & 63, quad = lane >> 4, ln = lane & 15;
  const int qw = wave & 3;   // q-row group (16 rows)
  const int kh = wave >> 2;  // k-half of each 64-row tile
  const int p = blockIdx.x >> 5;   // pair: q-tiles p and 31-p (0..15)
  const int bh = blockIdx.x & 31;  // same-bh -> same XCD (mod-8)
  const int b = bh >> 4, h = bh & 15;
  const int qA = p * 64, qB = (31 - p) * 64;
  const int ntiles = 32 - p;       // A active for kt <= p; B for all
  const size_t rs = 3072;
  const size_t base = (size_t)b * 2048 * rs;

  // Q as B-operand frags: B[d=quad*8+j][q=ln] = Q[q][d]  (dup across kh)
  const size_t qoffA = base + (size_t)(qA + qw * 16 + ln) * rs + h * 64;
  const size_t qoffB = base + (size_t)(qB + qw * 16 + ln) * rs + h * 64;
  bf16x8 qfA0 = *(const bf16x8*)&qkv[qoffA + quad * 8];
  bf16x8 qfA1 = *(const bf16x8*)&qkv[qoffA + 32 + quad * 8];
  bf16x8 qfB0 = *(const bf16x8*)&qkv[qoffB + quad * 8];
  bf16x8 qfB1 = *(const bf16x8*)&qkv[qoffB + 32 + quad * 8];

  // O^T accumulators (per k-half partial): rows d = ct*16+quad*4+r, col q=ln
  f32x4 oA[4], oB[4];
  f32x4 lAv = (f32x4){0.f, 0.f, 0.f, 0.f};
  f32x4 lBv = (f32x4){0.f, 0.f, 0.f, 0.f};
  for (int ct = 0; ct < 4; ct++) {
    oA[ct] = (f32x4){0.f, 0.f, 0.f, 0.f};
    oB[ct] = (f32x4){0.f, 0.f, 0.f, 0.f};
  }

  // staging: role split. kh=0 waves stage V, kh=1 waves stage K, each using
  // the verified 256-thread maps on t256 = t & 255.
  const int t256 = t & 255;
  const int r0 = t256 >> 3, c0 = (t256 & 7) * 8;
  const int wav4 = t256 >> 6;  // == r0>>3
  const int ksA = r0 * KP + (((t256 & 7) + wav4) & 7) * 8;
  const int ksB2 = (r0 + 32) * KP + (((t256 & 7) + wav4 + 4) & 7) * 8;
  const int vkoff = ((((r0 >> 2) + (t256 & 7)) & 7)) * 8 + 2 * (r0 & 3);

  const bf16_t* gp0;
  const bf16_t* gp1;
  if (kh) {  // K stager: rows r0, r0+32
    gp0 = &qkv[base + 1024 + h * 64 + (size_t)r0 * rs + c0];
    gp1 = gp0 + (size_t)32 * rs;
  } else {   // V stager: rows 2*r0, 2*r0+1
    gp0 = &qkv[base + 2048 + h * 64 + (size_t)(2 * r0) * rs + c0];
    gp1 = gp0 + rs;
  }
  const size_t tstep = (size_t)64 * rs;

  // tile 0 into regs (role-shared register pair)
  bf16x8 s0 = *(const bf16x8*)gp0; gp0 += tstep;
  bf16x8 s1 = *(const bf16x8*)gp1; gp1 += tstep;

  const int qgA = qA + qw * 16 + ln;  // lane's q (S^T column), set A
  const int qgB = qB + qw * 16 + ln;

  auto stage_to = [&](int buf) {
    if (kh) {
      bf16_t* KsW = &KsB[buf * BUF];
      *(bf16x8*)&KsW[ksA] = s0;
      *(bf16x8*)&KsW[ksB2] = s1;
    } else {
      bf16_t* VtW = &VtB[buf * BUF];
#pragma unroll
      for (int j = 0; j < 8; j++) {
        bf16x2 w2 = {s0[j], s1[j]};
        *(bf16x2*)&VtW[(c0 + j) * VP + vkoff] = w2;
      }
    }
  };
  auto prefetch = [&]() {
    s0 = *(const bf16x8*)gp0; gp0 += tstep;
    s1 = *(const bf16x8*)gp1; gp1 += tstep;
  };
  auto load_kfs = [&](const bf16_t* Ks, bf16x8* kf0s, bf16x8* kf1s) {
#pragma unroll
    for (int sh = 0; sh < 2; sh++) {
      const int st = kh * 2 + sh;
      const int krow = st * 16 + ln;
      const int rot = 2 * st + (ln >> 3);
      kf0s[sh] = *(const bf16x8*)&Ks[krow * KP + ((quad + rot) & 7) * 8];
      kf1s[sh] = *(const bf16x8*)&Ks[krow * KP + ((quad + 4 + rot) & 7) * 8];
    }
  };
  auto qk_block = [&](const bf16x8* kf0s, const bf16x8* kf1s, bf16x8 q0,
                      bf16x8 q1, f32x4& lxv, bf16x8& Bp, bool masked,
                      int kbase, int qg) {
    u32x4 u;
#pragma unroll
    for (int sh = 0; sh < 2; sh++) {
      f32x4 s = (f32x4){0.f, 0.f, 0.f, 0.f};
      __builtin_amdgcn_s_setprio(1);
      s = MFMA16(kf0s[sh], q0, s);
      s = MFMA16(kf1s[sh], q1, s);
      __builtin_amdgcn_s_setprio(0);
      const int k0g = kbase + (kh * 2 + sh) * 16 + quad * 4;
      float pv[4];
#pragma unroll
      for (int r = 0; r < 4; r++) {
        float e = __builtin_amdgcn_exp2f(fmaf(s[r], SCALE_L2E, ROUND_B));
        if (masked && (k0g + r > qg)) e = 0.f;
        lxv[r] += e;
        pv[r] = e;
      }
      u[sh * 2] = pack2(pv[0], pv[1]);
      u[sh * 2 + 1] = pack2(pv[2], pv[3]);
    }
    Bp = __builtin_bit_cast(bf16x8, u);
  };
  auto load_vfs = [&](const bf16_t* Vt, bf16x8* A8s) {
#pragma unroll
    for (int ct = 0; ct < 4; ct++) {
      const int dd = ct * 16 + ln;
      const int bc = (quad >> 1) + 2 * ct + (ln >> 3);
      const int cA = (4 * kh + bc) & 7;
      const int cB = (4 * kh + 2 + bc) & 7;
      bf16x4 v0 = *(const bf16x4*)&Vt[dd * VP + cA * 8 + (quad & 1) * 4];
      bf16x4 v1 = *(const bf16x4*)&Vt[dd * VP + cB * 8 + (quad & 1) * 4];
      A8s[ct] = __builtin_shufflevector(v0, v1, 0, 1, 2, 3, 4, 5, 6, 7);
    }
  };

  // main body for one k-tile. hasA/maskA/maskB are literals at call sites.
  auto body = [&](int kt, bool hasA, bool maskA, bool maskB) {
    if (kt + 1 < ntiles) {
      stage_to((kt + 1) & 1);
      if (kt + 2 < ntiles) prefetch();
    }
    const bf16_t* Ks = &KsB[(kt & 1) * BUF];
    const bf16_t* Vt = &VtB[(kt & 1) * BUF];
    bf16x8 kf0s[2], kf1s[2];
    load_kfs(Ks, kf0s, kf1s);
    bf16x8 BpA, BpB;
    if (hasA) qk_block(kf0s, kf1s, qfA0, qfA1, lAv, BpA, maskA, kt * 64, qgA);
    qk_block(kf0s, kf1s, qfB0, qfB1, lBv, BpB, maskB, kt * 64, qgB);
    bf16x8 A8s[4];
    load_vfs(Vt, A8s);
    __builtin_amdgcn_s_setprio(1);
#pragma unroll
    for (int ct = 0; ct < 4; ct++) {
      if (hasA) oA[ct] = MFMA16(A8s[ct], BpA, oA[ct]);
      oB[ct] = MFMA16(A8s[ct], BpB, oB[ct]);
    }
    __builtin_amdgcn_s_setprio(0);
    if (kt + 1 < ntiles) __syncthreads();
  };

  // prologue: tile 0 into buf0, prefetch tile 1, sync
  stage_to(0);
  if (ntiles > 1) prefetch();
  __syncthreads();

  // peeled phases: [0,p) AB | p A-diag | (p,31-p) B-only | 31-p B-diag
  for (int kt = 0; kt < p; kt++) body(kt, true, false, false);
  body(p, true, true, false);
  for (int kt = p + 1; kt < 31 - p; kt++) body(kt, false, false, false);
  body(31 - p, false, false, true);

  // per-wave l: fold f32x4 chains, sum across the 4 quads (k within half)
  float lAx = (lAv[0] + lAv[1]) + (lAv[2] + lAv[3]);
  float lBx = (lBv[0] + lBv[1]) + (lBv[2] + lBv[3]);
  lAx += __shfl_xor(lAx, 16);
  lAx += __shfl_xor(lAx, 32);
  lBx += __shfl_xor(lBx, 16);
  lBx += __shfl_xor(lBx, 32);

  // cross-half reduction via dead K/V LDS. Scratch: 4 ct x 256 idx f32x4
  // (16384 B) + 256 f32 l (1024 B) per buffer; KsB/VtB are 18432 B each.
  __syncthreads();  // all tile reads complete before LDS reuse
  float* redA = (float*)KsB;
  float* redB = (float*)VtB;
  const int idx = qw * 64 + lane;  // partner wave (qw, kh^1) has same idx
  if (kh) {
#pragma unroll
    for (int ct = 0; ct < 4; ct++) {
      *(f32x4*)&redA[(ct * 256 + idx) * 4] = oA[ct];
      *(f32x4*)&redB[(ct * 256 + idx) * 4] = oB[ct];
    }
    redA[4096 + idx] = lAx;
    redB[4096 + idx] = lBx;
  }
  __syncthreads();
  if (!kh) {
#pragma unroll
    for (int ct = 0; ct < 4; ct++) {
      oA[ct] += *(const f32x4*)&redA[(ct * 256 + idx) * 4];
      oB[ct] += *(const f32x4*)&redB[(ct * 256 + idx) * 4];
    }
    lAx += redA[4096 + idx];
    lBx += redB[4096 + idx];
    const float invA = __builtin_amdgcn_rcpf(lAx);
    const float invB = __builtin_amdgcn_rcpf(lBx);
    const int ocol = h * 64 + quad * 4;
#pragma unroll
    for (int ct = 0; ct < 4; ct++) {
      bf16x4 wa, wb;
#pragma unroll
      for (int r = 0; r < 4; r++) {
        wa[r] = (bf16_t)(oA[ct][r] * invA);
        wb[r] = (bf16_t)(oB[ct][r] * invB);
      }
      *(bf16x4*)&out[(size_t)(b * 2048 + qgA) * 1024 + ocol + ct * 16] = wa;
      *(bf16x4*)&out[(size_t)(b * 2048 + qgB) * 1024 + ocol + ct * 16] = wb;
    }
  }
}

extern "C" void kernel_launch(void* const* d_in, const int* in_sizes, int n_in,
                              void* d_out, int out_size, void* d_ws, size_t ws_size,
                              hipStream_t stream) {
  const float* x     = (const float*)d_in[0];  // [2,2048,1024]
  const float* w_qkv = (const float*)d_in[1];  // [3072,1024]
  const float* b_qkv = (const float*)d_in[2];  // [3072]
  const float* w_o   = (const float*)d_in[3];  // [1024,1024]
  const float* b_o   = (const float*)d_in[4];  // [1024]
  float* out = (float*)d_out;                  // [2,2048,1024]

  // workspace (bf16): qkv | xbf/attn (aliased) | wqkv_bf | wo_bf  = 42 MB
  bf16_t* qkv   = (bf16_t*)d_ws;
  bf16_t* xbf   = qkv + (size_t)4096 * 3072;
  bf16_t* wqkvb = xbf + (size_t)4096 * 1024;
  bf16_t* wob   = wqkvb + (size_t)3072 * 1024;
  bf16_t* attn  = xbf;  // x dead after GEMM1

  const int na = 4096 * 1024, nb = 3072 * 1024, nc = 1024 * 1024;
  convert3_f32_bf16<<<dim3((na + nb + nc) / (256 * 8)), 256, 0, stream>>>(
      x, na, w_qkv, nb, w_o, nc, xbf, wqkvb, wob);

  // 1) qkv = x @ w_qkv^T + b_qkv   (128^2 dbuf 1-barrier, 768 blocks, 2/CU)
  gemm128db<<<dim3(3072 / 128, 4096 / 128), 256, 0, stream>>>(
      xbf, wqkvb, b_qkv, qkv, 4096, 3072, 1024);
  // 2) causal attention, paired q-tiles, k-split 8-wave: EXACTLY 512 blocks
  attn_kernel<<<dim3(512), 512, 0, stream>>>(qkv, attn);
  // 3) out = attn @ w_o^T + b_o    (128x64 tiles -> 512 blocks, 2/CU)
  gemm_bt_bias<float, 64><<<dim3(1024 / 64, 4096 / 128), 256, 0, stream>>>(
      attn, wob, b_o, out, 4096, 1024, 1024);
}

// Round 10
// 172.805 us; speedup vs baseline: 1.0283x; 1.0265x over previous
//
#include <hip/hip_runtime.h>
#include <hip/hip_bf16.h>
#include <math.h>

typedef __bf16 bf16_t;
typedef __bf16 bf16x8 __attribute__((ext_vector_type(8)));
typedef __bf16 bf16x4 __attribute__((ext_vector_type(4)));
typedef __bf16 bf16x2 __attribute__((ext_vector_type(2)));
typedef float f32x4 __attribute__((ext_vector_type(4)));
typedef unsigned u32x4 __attribute__((ext_vector_type(4)));

// scale 1/sqrt(1024) folded with log2(e), plus half-ulp rounding bias
// (x * 2^0.0028169 = x * (1+2^-9)) so perm-truncation rounds on average.
#define SCALE_L2E 0.045084234f
#define ROUND_B 0.0028169f

#define MFMA16(a, b, c) __builtin_amdgcn_mfma_f32_16x16x32_bf16(a, b, c, 0, 0, 0)

// pack two f32 into bf16x2 (truncate): dst = (hi16(b) << 16) | hi16(a)
__device__ __forceinline__ unsigned pack2(float a, float b) {
  return __builtin_amdgcn_perm(__builtin_bit_cast(unsigned, b),
                               __builtin_bit_cast(unsigned, a), 0x07060302u);
}

// ---------------------------------------------------------------------------
// fused f32 -> bf16 convert of three buffers (x, w_qkv, w_o), 8 elems/thread
// ---------------------------------------------------------------------------
__global__ void convert3_f32_bf16(const float* __restrict__ a, int na,
                                  const float* __restrict__ b, int nb,
                                  const float* __restrict__ c, int nc,
                                  bf16_t* __restrict__ oa, bf16_t* __restrict__ ob,
                                  bf16_t* __restrict__ oc) {
  int i = (blockIdx.x * blockDim.x + threadIdx.x) * 8;
  const float* src;
  bf16_t* dst;
  int off;
  if (i < na) { src = a; dst = oa; off = i; }
  else if (i < na + nb) { src = b; dst = ob; off = i - na; }
  else if (i < na + nb + nc) { src = c; dst = oc; off = i - na - nb; }
  else return;
  float4 u = *(const float4*)&src[off];
  float4 v = *(const float4*)&src[off + 4];
  bf16x8 w = {(bf16_t)u.x, (bf16_t)u.y, (bf16_t)u.z, (bf16_t)u.w,
              (bf16_t)v.x, (bf16_t)v.y, (bf16_t)v.z, (bf16_t)v.w};
  *(bf16x8*)&dst[off] = w;
}

#define GLOBAL_AS __attribute__((address_space(1)))
#define LDS_AS __attribute__((address_space(3)))
__device__ __forceinline__ void g2l16(const void* g, void* l) {
  __builtin_amdgcn_global_load_lds((const GLOBAL_AS void*)g, (LDS_AS void*)l,
                                   16, 0, 0);
}

// ---------------------------------------------------------------------------
// BM x 128 BT-GEMM, BK=64 double-buffer, ONE barrier per K-tile (R8/R10).
// C[m,n] = sum_k A[m,k]*B[n,k] + bias[n].
// BM=128 (GEMM1): 2x2 waves, 64x64/wave, 64 KiB LDS, 768 blocks (2/CU).
// BM=64  (GEMM2, R10): 32x64/wave (acc[2][4], 16 MFMA/tile), 48 KiB LDS,
//   grid (1024/128)x(4096/64) = 512 blocks = exactly 2/CU — replaces the
//   m97-style BN=64 template (2 barriers per 8 MFMA/wave; ~343 TF ladder).
//   R5 lesson honored: co-residency >= 2 (the 256-block/1-CU shape lost 5us).
// Per tile: issue next tile's staging (g2l16) BEFORE compute, then ds_read
// frags + MFMA with no inline waits (compiler emits fine-grained lgkmcnt),
// then one __syncthreads() = vmcnt(0)+lgkmcnt(0)+barrier drain.
// Swizzle (T2, verbatim from the refcheck-verified gemm256): stored k-chunk
// (lane&7) holds logical chunk (lane&7)^(lane>>3); global source pre-applies
// the involution (rule 21); read slot = (quad ^ (ln&7)) ^ (4*sk). 2-way
// conflicts (free, m136); measured 0 SQ_LDS_BANK_CONFLICT.
// ---------------------------------------------------------------------------
template <int BM, typename TC>
__launch_bounds__(256, 2)
__global__ void gemm128db(const bf16_t* __restrict__ A,
                          const bf16_t* __restrict__ B,
                          const float* __restrict__ bias,
                          TC* __restrict__ C,
                          int M, int N, int K) {
  constexpr int MF = BM / 32;  // m-frags per wave (BM/2 rows / 16)
  __shared__ __align__(16) bf16_t Ab[2][BM * 64];
  __shared__ __align__(16) bf16_t Bb[2][128 * 64];

  const int tid = threadIdx.x;
  const int wave = tid >> 6, lane = tid & 63, quad = lane >> 4, ln = lane & 15;
  const int wm = wave >> 1, wn = wave & 1;  // 2M x 2N
  const int m0 = blockIdx.y * BM, n0 = blockIdx.x * 128;
  const int nt = K >> 6;

  const int rowoff = wave * 8 + (lane >> 3);          // 0..31
  const int c8 = ((lane & 7) ^ (lane >> 3)) * 8;      // inverse-swizzled src
  const int w8row = wave * 8;
  const bf16_t* Arow0 = A + (size_t)(m0 + rowoff) * K + c8;
  const bf16_t* Brow0 = B + (size_t)(n0 + rowoff) * K + c8;

  auto stA = [&](int tl) {
    const bf16_t* g = Arow0 + (size_t)tl * 64;
    bf16_t* l = &Ab[tl & 1][w8row * 64];
#pragma unroll
    for (int rr = 0; rr < BM; rr += 32)
      g2l16(g + (size_t)rr * K, l + rr * 64);
  };
  auto stB = [&](int tl) {
    const bf16_t* g = Brow0 + (size_t)tl * 64;
    bf16_t* l = &Bb[tl & 1][w8row * 64];
#pragma unroll
    for (int rr = 0; rr < 128; rr += 32)
      g2l16(g + (size_t)rr * K, l + rr * 64);
  };

  const int cswl = (quad ^ (ln & 7)) * 8;
  const int aBase = (wm * (BM / 2) + ln) * 64;
  const int bBase = (wn * 64 + ln) * 64;

  f32x4 acc[MF][4];
#pragma unroll
  for (int i = 0; i < MF; i++)
#pragma unroll
    for (int j = 0; j < 4; j++) acc[i][j] = (f32x4){0.f, 0.f, 0.f, 0.f};

  bf16x8 af[MF][2], bfr[4][2];

  auto ldA = [&](int buf) {
#pragma unroll
    for (int mf = 0; mf < MF; ++mf)
#pragma unroll
      for (int sk = 0; sk < 2; ++sk)
        af[mf][sk] = *(const bf16x8*)&Ab[buf][aBase + mf * 1024 +
                                             (cswl ^ (sk << 5))];
  };
  auto ldB = [&](int buf) {
#pragma unroll
    for (int nf = 0; nf < 4; ++nf)
#pragma unroll
      for (int sk = 0; sk < 2; ++sk)
        bfr[nf][sk] = *(const bf16x8*)&Bb[buf][bBase + nf * 1024 +
                                               (cswl ^ (sk << 5))];
  };
  auto mm = [&]() {
#pragma unroll
    for (int mf = 0; mf < MF; ++mf)
#pragma unroll
      for (int nf = 0; nf < 4; ++nf) {
        f32x4 c = acc[mf][nf];
        c = MFMA16(af[mf][0], bfr[nf][0], c);
        c = MFMA16(af[mf][1], bfr[nf][1], c);
        acc[mf][nf] = c;
      }
  };

  stA(0); stB(0);
  __syncthreads();

  for (int tl = 0; tl < nt; ++tl) {
    const int buf = tl & 1;
    if (tl + 1 < nt) { stA(tl + 1); stB(tl + 1); }
    ldA(buf);
    ldB(buf);
    mm();
    __syncthreads();
  }

#pragma unroll
  for (int nf = 0; nf < 4; ++nf) {
    const int col = n0 + wn * 64 + nf * 16 + ln;
    const float bv = bias[col];
#pragma unroll
    for (int mf = 0; mf < MF; ++mf) {
      const int row = m0 + wm * (BM / 2) + mf * 16 + quad * 4;
#pragma unroll
      for (int r = 0; r < 4; ++r)
        C[(size_t)(row + r) * N + col] = (TC)(acc[mf][nf][r] + bv);
    }
  }
}

// ---------------------------------------------------------------------------
// Causal attention, K-SPLIT 8-WAVE (R9, kept): paired q-tiles (p,31-p), 512
// blocks, 512 threads. Wave w = (q-group w&3, k-half w>>2). Same aggregate
// work as the 4-wave version (128 MFMA/tile, same LDS traffic) but 2x waves
// -> 4 waves/SIMD and per-wave serial chains halved (TLP fix for the R2-
// measured latency-boundness; R4's unpair failed because it DOUBLED LDS
// work — this doesn't). Staging by role: waves 0-3 stage V, waves 4-7 stage
// K, with the verified 256-thread maps on t&255. Epilogue: cross-half O/l
// reduction through the dead K/V LDS buffers. R3 XCD map (bh low 5 bits),
// R6 f32x4 l-chains kept. GRID MUST BE 512.
// ---------------------------------------------------------------------------
__launch_bounds__(512, 4)
__global__ void attn_kernel(const bf16_t* __restrict__ qkv,
                            bf16_t* __restrict__ out) {
  constexpr int KP = 72, VP = 72;
  constexpr int BUF = 64 * KP;  // elems per K (or V) buffer
  __shared__ __align__(16) bf16_t KsB[2 * BUF];  // [buf][k][d], swizzled
  __shared__ __align__(16) bf16_t VtB[2 * BUF];  // [buf][d][k], swizzled

  const int t = threadIdx.x;
  const int wave = t >> 6, lane = t & 63, quad = lane >> 4, ln = lane & 15;
  const int qw = wave & 3;   // q-row group (16 rows)
  const int kh = wave >> 2;  // k-half of each 64-row tile
  const int p = blockIdx.x >> 5;   // pair: q-tiles p and 31-p (0..15)
  const int bh = blockIdx.x & 31;  // same-bh -> same XCD (mod-8)
  const int b = bh >> 4, h = bh & 15;
  const int qA = p * 64, qB = (31 - p) * 64;
  const int ntiles = 32 - p;       // A active for kt <= p; B for all
  const size_t rs = 3072;
  const size_t base = (size_t)b * 2048 * rs;

  // Q as B-operand frags: B[d=quad*8+j][q=ln] = Q[q][d]  (dup across kh)
  const size_t qoffA = base + (size_t)(qA + qw * 16 + ln) * rs + h * 64;
  const size_t qoffB = base + (size_t)(qB + qw * 16 + ln) * rs + h * 64;
  bf16x8 qfA0 = *(const bf16x8*)&qkv[qoffA + quad * 8];
  bf16x8 qfA1 = *(const bf16x8*)&qkv[qoffA + 32 + quad * 8];
  bf16x8 qfB0 = *(const bf16x8*)&qkv[qoffB + quad * 8];
  bf16x8 qfB1 = *(const bf16x8*)&qkv[qoffB + 32 + quad * 8];

  // O^T accumulators (per k-half partial): rows d = ct*16+quad*4+r, col q=ln
  f32x4 oA[4], oB[4];
  f32x4 lAv = (f32x4){0.f, 0.f, 0.f, 0.f};
  f32x4 lBv = (f32x4){0.f, 0.f, 0.f, 0.f};
  for (int ct = 0; ct < 4; ct++) {
    oA[ct] = (f32x4){0.f, 0.f, 0.f, 0.f};
    oB[ct] = (f32x4){0.f, 0.f, 0.f, 0.f};
  }

  // staging: role split. kh=0 waves stage V, kh=1 waves stage K, each using
  // the verified 256-thread maps on t256 = t & 255.
  const int t256 = t & 255;
  const int r0 = t256 >> 3, c0 = (t256 & 7) * 8;
  const int wav4 = t256 >> 6;  // == r0>>3
  const int ksA = r0 * KP + (((t256 & 7) + wav4) & 7) * 8;
  const int ksB2 = (r0 + 32) * KP + (((t256 & 7) + wav4 + 4) & 7) * 8;
  const int vkoff = ((((r0 >> 2) + (t256 & 7)) & 7)) * 8 + 2 * (r0 & 3);

  const bf16_t* gp0;
  const bf16_t* gp1;
  if (kh) {  // K stager: rows r0, r0+32
    gp0 = &qkv[base + 1024 + h * 64 + (size_t)r0 * rs + c0];
    gp1 = gp0 + (size_t)32 * rs;
  } else {   // V stager: rows 2*r0, 2*r0+1
    gp0 = &qkv[base + 2048 + h * 64 + (size_t)(2 * r0) * rs + c0];
    gp1 = gp0 + rs;
  }
  const size_t tstep = (size_t)64 * rs;

  // tile 0 into regs (role-shared register pair)
  bf16x8 s0 = *(const bf16x8*)gp0; gp0 += tstep;
  bf16x8 s1 = *(const bf16x8*)gp1; gp1 += tstep;

  const int qgA = qA + qw * 16 + ln;  // lane's q (S^T column), set A
  const int qgB = qB + qw * 16 + ln;

  auto stage_to = [&](int buf) {
    if (kh) {
      bf16_t* KsW = &KsB[buf * BUF];
      *(bf16x8*)&KsW[ksA] = s0;
      *(bf16x8*)&KsW[ksB2] = s1;
    } else {
      bf16_t* VtW = &VtB[buf * BUF];
#pragma unroll
      for (int j = 0; j < 8; j++) {
        bf16x2 w2 = {s0[j], s1[j]};
        *(bf16x2*)&VtW[(c0 + j) * VP + vkoff] = w2;
      }
    }
  };
  auto prefetch = [&]() {
    s0 = *(const bf16x8*)gp0; gp0 += tstep;
    s1 = *(const bf16x8*)gp1; gp1 += tstep;
  };
  auto load_kfs = [&](const bf16_t* Ks, bf16x8* kf0s, bf16x8* kf1s) {
#pragma unroll
    for (int sh = 0; sh < 2; sh++) {
      const int st = kh * 2 + sh;
      const int krow = st * 16 + ln;
      const int rot = 2 * st + (ln >> 3);
      kf0s[sh] = *(const bf16x8*)&Ks[krow * KP + ((quad + rot) & 7) * 8];
      kf1s[sh] = *(const bf16x8*)&Ks[krow * KP + ((quad + 4 + rot) & 7) * 8];
    }
  };
  auto qk_block = [&](const bf16x8* kf0s, const bf16x8* kf1s, bf16x8 q0,
                      bf16x8 q1, f32x4& lxv, bf16x8& Bp, bool masked,
                      int kbase, int qg) {
    u32x4 u;
#pragma unroll
    for (int sh = 0; sh < 2; sh++) {
      f32x4 s = (f32x4){0.f, 0.f, 0.f, 0.f};
      __builtin_amdgcn_s_setprio(1);
      s = MFMA16(kf0s[sh], q0, s);
      s = MFMA16(kf1s[sh], q1, s);
      __builtin_amdgcn_s_setprio(0);
      const int k0g = kbase + (kh * 2 + sh) * 16 + quad * 4;
      float pv[4];
#pragma unroll
      for (int r = 0; r < 4; r++) {
        float e = __builtin_amdgcn_exp2f(fmaf(s[r], SCALE_L2E, ROUND_B));
        if (masked && (k0g + r > qg)) e = 0.f;
        lxv[r] += e;
        pv[r] = e;
      }
      u[sh * 2] = pack2(pv[0], pv[1]);
      u[sh * 2 + 1] = pack2(pv[2], pv[3]);
    }
    Bp = __builtin_bit_cast(bf16x8, u);
  };
  auto load_vfs = [&](const bf16_t* Vt, bf16x8* A8s) {
#pragma unroll
    for (int ct = 0; ct < 4; ct++) {
      const int dd = ct * 16 + ln;
      const int bc = (quad >> 1) + 2 * ct + (ln >> 3);
      const int cA = (4 * kh + bc) & 7;
      const int cB = (4 * kh + 2 + bc) & 7;
      bf16x4 v0 = *(const bf16x4*)&Vt[dd * VP + cA * 8 + (quad & 1) * 4];
      bf16x4 v1 = *(const bf16x4*)&Vt[dd * VP + cB * 8 + (quad & 1) * 4];
      A8s[ct] = __builtin_shufflevector(v0, v1, 0, 1, 2, 3, 4, 5, 6, 7);
    }
  };

  // main body for one k-tile. hasA/maskA/maskB are literals at call sites.
  auto body = [&](int kt, bool hasA, bool maskA, bool maskB) {
    if (kt + 1 < ntiles) {
      stage_to((kt + 1) & 1);
      if (kt + 2 < ntiles) prefetch();
    }
    const bf16_t* Ks = &KsB[(kt & 1) * BUF];
    const bf16_t* Vt = &VtB[(kt & 1) * BUF];
    bf16x8 kf0s[2], kf1s[2];
    load_kfs(Ks, kf0s, kf1s);
    bf16x8 BpA, BpB;
    if (hasA) qk_block(kf0s, kf1s, qfA0, qfA1, lAv, BpA, maskA, kt * 64, qgA);
    qk_block(kf0s, kf1s, qfB0, qfB1, lBv, BpB, maskB, kt * 64, qgB);
    bf16x8 A8s[4];
    load_vfs(Vt, A8s);
    __builtin_amdgcn_s_setprio(1);
#pragma unroll
    for (int ct = 0; ct < 4; ct++) {
      if (hasA) oA[ct] = MFMA16(A8s[ct], BpA, oA[ct]);
      oB[ct] = MFMA16(A8s[ct], BpB, oB[ct]);
    }
    __builtin_amdgcn_s_setprio(0);
    if (kt + 1 < ntiles) __syncthreads();
  };

  // prologue: tile 0 into buf0, prefetch tile 1, sync
  stage_to(0);
  if (ntiles > 1) prefetch();
  __syncthreads();

  // peeled phases: [0,p) AB | p A-diag | (p,31-p) B-only | 31-p B-diag
  for (int kt = 0; kt < p; kt++) body(kt, true, false, false);
  body(p, true, true, false);
  for (int kt = p + 1; kt < 31 - p; kt++) body(kt, false, false, false);
  body(31 - p, false, false, true);

  // per-wave l: fold f32x4 chains, sum across the 4 quads (k within half)
  float lAx = (lAv[0] + lAv[1]) + (lAv[2] + lAv[3]);
  float lBx = (lBv[0] + lBv[1]) + (lBv[2] + lBv[3]);
  lAx += __shfl_xor(lAx, 16);
  lAx += __shfl_xor(lAx, 32);
  lBx += __shfl_xor(lBx, 16);
  lBx += __shfl_xor(lBx, 32);

  // cross-half reduction via dead K/V LDS. Scratch: 4 ct x 256 idx f32x4
  // (16384 B) + 256 f32 l (1024 B) per buffer; KsB/VtB are 18432 B each.
  __syncthreads();  // all tile reads complete before LDS reuse
  float* redA = (float*)KsB;
  float* redB = (float*)VtB;
  const int idx = qw * 64 + lane;  // partner wave (qw, kh^1) has same idx
  if (kh) {
#pragma unroll
    for (int ct = 0; ct < 4; ct++) {
      *(f32x4*)&redA[(ct * 256 + idx) * 4] = oA[ct];
      *(f32x4*)&redB[(ct * 256 + idx) * 4] = oB[ct];
    }
    redA[4096 + idx] = lAx;
    redB[4096 + idx] = lBx;
  }
  __syncthreads();
  if (!kh) {
#pragma unroll
    for (int ct = 0; ct < 4; ct++) {
      oA[ct] += *(const f32x4*)&redA[(ct * 256 + idx) * 4];
      oB[ct] += *(const f32x4*)&redB[(ct * 256 + idx) * 4];
    }
    lAx += redA[4096 + idx];
    lBx += redB[4096 + idx];
    const float invA = __builtin_amdgcn_rcpf(lAx);
    const float invB = __builtin_amdgcn_rcpf(lBx);
    const int ocol = h * 64 + quad * 4;
#pragma unroll
    for (int ct = 0; ct < 4; ct++) {
      bf16x4 wa, wb;
#pragma unroll
      for (int r = 0; r < 4; r++) {
        wa[r] = (bf16_t)(oA[ct][r] * invA);
        wb[r] = (bf16_t)(oB[ct][r] * invB);
      }
      *(bf16x4*)&out[(size_t)(b * 2048 + qgA) * 1024 + ocol + ct * 16] = wa;
      *(bf16x4*)&out[(size_t)(b * 2048 + qgB) * 1024 + ocol + ct * 16] = wb;
    }
  }
}

extern "C" void kernel_launch(void* const* d_in, const int* in_sizes, int n_in,
                              void* d_out, int out_size, void* d_ws, size_t ws_size,
                              hipStream_t stream) {
  const float* x     = (const float*)d_in[0];  // [2,2048,1024]
  const float* w_qkv = (const float*)d_in[1];  // [3072,1024]
  const float* b_qkv = (const float*)d_in[2];  // [3072]
  const float* w_o   = (const float*)d_in[3];  // [1024,1024]
  const float* b_o   = (const float*)d_in[4];  // [1024]
  float* out = (float*)d_out;                  // [2,2048,1024]

  // workspace (bf16): qkv | xbf/attn (aliased) | wqkv_bf | wo_bf  = 42 MB
  bf16_t* qkv   = (bf16_t*)d_ws;
  bf16_t* xbf   = qkv + (size_t)4096 * 3072;
  bf16_t* wqkvb = xbf + (size_t)4096 * 1024;
  bf16_t* wob   = wqkvb + (size_t)3072 * 1024;
  bf16_t* attn  = xbf;  // x dead after GEMM1

  const int na = 4096 * 1024, nb = 3072 * 1024, nc = 1024 * 1024;
  convert3_f32_bf16<<<dim3((na + nb + nc) / (256 * 8)), 256, 0, stream>>>(
      x, na, w_qkv, nb, w_o, nc, xbf, wqkvb, wob);

  // 1) qkv = x @ w_qkv^T + b_qkv   (128^2 dbuf 1-barrier, 768 blocks, 2/CU)
  gemm128db<128, bf16_t><<<dim3(3072 / 128, 4096 / 128), 256, 0, stream>>>(
      xbf, wqkvb, b_qkv, qkv, 4096, 3072, 1024);
  // 2) causal attention, paired q-tiles, k-split 8-wave: EXACTLY 512 blocks
  attn_kernel<<<dim3(512), 512, 0, stream>>>(qkv, attn);
  // 3) out = attn @ w_o^T + b_o    (64x128 dbuf 1-barrier, 8x64 = 512 blocks,
  //    2/CU — replaces the m97 BN=64 2-barrier template)
  gemm128db<64, float><<<dim3(1024 / 128, 4096 / 64), 256, 0, stream>>>(
      attn, wob, b_o, out, 4096, 1024, 1024);
}

// Round 11
// 169.246 us; speedup vs baseline: 1.0500x; 1.0210x over previous
//
#include <hip/hip_runtime.h>
#include <hip/hip_bf16.h>
#include <math.h>

typedef __bf16 bf16_t;
typedef __bf16 bf16x8 __attribute__((ext_vector_type(8)));
typedef __bf16 bf16x4 __attribute__((ext_vector_type(4)));
typedef __bf16 bf16x2 __attribute__((ext_vector_type(2)));
typedef float f32x4 __attribute__((ext_vector_type(4)));
typedef unsigned u32x4 __attribute__((ext_vector_type(4)));

// scale 1/sqrt(1024) folded with log2(e), plus half-ulp rounding bias
// (x * 2^0.0028169 = x * (1+2^-9)) so perm-truncation rounds on average.
#define SCALE_L2E 0.045084234f
#define ROUND_B 0.0028169f

#define MFMA16(a, b, c) __builtin_amdgcn_mfma_f32_16x16x32_bf16(a, b, c, 0, 0, 0)

// pack two f32 into bf16x2 (truncate): dst = (hi16(b) << 16) | hi16(a)
__device__ __forceinline__ unsigned pack2(float a, float b) {
  return __builtin_amdgcn_perm(__builtin_bit_cast(unsigned, b),
                               __builtin_bit_cast(unsigned, a), 0x07060302u);
}

// ---------------------------------------------------------------------------
// fused f32 -> bf16 convert of three buffers (x, w_qkv, w_o), 8 elems/thread
// ---------------------------------------------------------------------------
__global__ void convert3_f32_bf16(const float* __restrict__ a, int na,
                                  const float* __restrict__ b, int nb,
                                  const float* __restrict__ c, int nc,
                                  bf16_t* __restrict__ oa, bf16_t* __restrict__ ob,
                                  bf16_t* __restrict__ oc) {
  int i = (blockIdx.x * blockDim.x + threadIdx.x) * 8;
  const float* src;
  bf16_t* dst;
  int off;
  if (i < na) { src = a; dst = oa; off = i; }
  else if (i < na + nb) { src = b; dst = ob; off = i - na; }
  else if (i < na + nb + nc) { src = c; dst = oc; off = i - na - nb; }
  else return;
  float4 u = *(const float4*)&src[off];
  float4 v = *(const float4*)&src[off + 4];
  bf16x8 w = {(bf16_t)u.x, (bf16_t)u.y, (bf16_t)u.z, (bf16_t)u.w,
              (bf16_t)v.x, (bf16_t)v.y, (bf16_t)v.z, (bf16_t)v.w};
  *(bf16x8*)&dst[off] = w;
}

#define GLOBAL_AS __attribute__((address_space(1)))
#define LDS_AS __attribute__((address_space(3)))
__device__ __forceinline__ void g2l16(const void* g, void* l) {
  __builtin_amdgcn_global_load_lds((const GLOBAL_AS void*)g, (LDS_AS void*)l,
                                   16, 0, 0);
}

// ---------------------------------------------------------------------------
// 128x128 BT-GEMM, BK=32 double-buffer, ONE barrier per K-tile (R11, GEMM1).
// C[m,n] = sum_k A[m,k]*B[n,k] + bias[n].
// Theory: all BK=64 variants capped at 2 blocks/CU (64 KiB LDS) and measured
// 43-48us / MfmaUtil ~19% / Occ 15% — the per-tile vmcnt(0)+barrier drain has
// at most ONE co-resident block to hide under. m97 evidence: the 128^2 BK=32
// structure reaches 912 TF at ~3 blocks/CU. This kernel: 32 KiB LDS total
// (2 buf x (128x32 A + 128x32 B)), VGPR ~80 -> 4-5 blocks/CU co-resident.
// Staging/read maps VERBATIM from the m97-style gemm_bt_bias that refcheck-
// passed in this file (R0-R4): stage row=lane>>2 per wave-half, stored chunk
// slot (lane&3) holds logical chunk (lane&3)^((lane>>3)&3); read slot
// (quad^((ln>>1)&3)) -> logical chunk quad (algebra: (row>>1)&3 == (ln>>1)&3
// since wm, mt*16 are multiples of 16). Dbuf safety = R8 argument: stage(t+1)
// writes buf^1; buf^1's readers (tile t-1) passed the prior barrier; the
// per-tile __syncthreads drains vmcnt before buf^1 is read. 16 MFMA/wave/tile,
// 32 tiles. No setprio (m190: null on non-phase-split GEMM).
// ---------------------------------------------------------------------------
__launch_bounds__(256, 4)
__global__ void gemm128k32(const bf16_t* __restrict__ A,
                           const bf16_t* __restrict__ B,
                           const float* __restrict__ bias,
                           bf16_t* __restrict__ C,
                           int M, int N, int K) {
  __shared__ __align__(16) bf16_t As[2][128 * 32];
  __shared__ __align__(16) bf16_t Bs[2][128 * 32];

  const int t = threadIdx.x;
  const int wave = t >> 6, lane = t & 63, quad = lane >> 4, ln = lane & 15;
  const int wm = (wave >> 1) * 64, wn = (wave & 1) * 64;
  const int m0 = blockIdx.y * 128, n0 = blockIdx.x * 128;
  const int nt = K >> 5;  // 32 K-tiles

  const int srow = lane >> 2;
  const int schunk = ((lane & 3) ^ ((lane >> 3) & 3)) * 8;
  const bf16_t* gA0 = &A[(size_t)(m0 + wave * 32 + srow) * K + schunk];
  const bf16_t* gA1 = gA0 + (size_t)16 * K;
  const bf16_t* gB0 = &B[(size_t)(n0 + wave * 32 + srow) * K + schunk];
  const bf16_t* gB1 = gB0 + (size_t)16 * K;

  const int cslot = (quad ^ ((ln >> 1) & 3)) * 8;

  f32x4 acc[4][4];
#pragma unroll
  for (int i = 0; i < 4; i++)
#pragma unroll
    for (int j = 0; j < 4; j++) acc[i][j] = (f32x4){0.f, 0.f, 0.f, 0.f};

  auto stage = [&](int tl) {
    const int buf = tl & 1;
    const int k0 = tl * 32;
    g2l16(gA0 + k0, &As[buf][(wave * 32) * 32]);
    g2l16(gA1 + k0, &As[buf][(wave * 32 + 16) * 32]);
    g2l16(gB0 + k0, &Bs[buf][(wave * 32) * 32]);
    g2l16(gB1 + k0, &Bs[buf][(wave * 32 + 16) * 32]);
  };

  // prologue: stage tile 0, drain, go.
  stage(0);
  __syncthreads();

  for (int tl = 0; tl < nt; ++tl) {
    const int buf = tl & 1;
    if (tl + 1 < nt) stage(tl + 1);  // HBM latency hides under this tile
    bf16x8 af[4], bfr[4];
#pragma unroll
    for (int mt = 0; mt < 4; mt++)
      af[mt] = *(const bf16x8*)&As[buf][(wm + mt * 16 + ln) * 32 + cslot];
#pragma unroll
    for (int nf = 0; nf < 4; nf++)
      bfr[nf] = *(const bf16x8*)&Bs[buf][(wn + nf * 16 + ln) * 32 + cslot];
#pragma unroll
    for (int mt = 0; mt < 4; mt++)
#pragma unroll
      for (int nf = 0; nf < 4; nf++)
        acc[mt][nf] = MFMA16(af[mt], bfr[nf], acc[mt][nf]);
    __syncthreads();  // vmcnt(0)+lgkmcnt(0)+barrier, once per tile
  }

#pragma unroll
  for (int nf = 0; nf < 4; nf++) {
    const int col = n0 + wn + nf * 16 + ln;
    const float bv = bias[col];
#pragma unroll
    for (int mt = 0; mt < 4; mt++) {
      const int row = m0 + wm + mt * 16 + quad * 4;
#pragma unroll
      for (int r = 0; r < 4; r++)
        C[(size_t)(row + r) * N + col] = (bf16_t)(acc[mt][nf][r] + bv);
    }
  }
}

// ---------------------------------------------------------------------------
// BM x 128 BT-GEMM, BK=64 double-buffer, ONE barrier per K-tile (R8/R10).
// Kept for GEMM2: BM=64, 48 KiB LDS, grid (1024/128)x(4096/64) = 512 blocks
// = exactly 2/CU (R5 lesson: co-residency >= 2). Swizzle verbatim from the
// refcheck-verified gemm256 lineage.
// ---------------------------------------------------------------------------
template <int BM, typename TC>
__launch_bounds__(256, 2)
__global__ void gemm128db(const bf16_t* __restrict__ A,
                          const bf16_t* __restrict__ B,
                          const float* __restrict__ bias,
                          TC* __restrict__ C,
                          int M, int N, int K) {
  constexpr int MF = BM / 32;  // m-frags per wave (BM/2 rows / 16)
  __shared__ __align__(16) bf16_t Ab[2][BM * 64];
  __shared__ __align__(16) bf16_t Bb[2][128 * 64];

  const int tid = threadIdx.x;
  const int wave = tid >> 6, lane = tid & 63, quad = lane >> 4, ln = lane & 15;
  const int wm = wave >> 1, wn = wave & 1;  // 2M x 2N
  const int m0 = blockIdx.y * BM, n0 = blockIdx.x * 128;
  const int nt = K >> 6;

  const int rowoff = wave * 8 + (lane >> 3);          // 0..31
  const int c8 = ((lane & 7) ^ (lane >> 3)) * 8;      // inverse-swizzled src
  const int w8row = wave * 8;
  const bf16_t* Arow0 = A + (size_t)(m0 + rowoff) * K + c8;
  const bf16_t* Brow0 = B + (size_t)(n0 + rowoff) * K + c8;

  auto stA = [&](int tl) {
    const bf16_t* g = Arow0 + (size_t)tl * 64;
    bf16_t* l = &Ab[tl & 1][w8row * 64];
#pragma unroll
    for (int rr = 0; rr < BM; rr += 32)
      g2l16(g + (size_t)rr * K, l + rr * 64);
  };
  auto stB = [&](int tl) {
    const bf16_t* g = Brow0 + (size_t)tl * 64;
    bf16_t* l = &Bb[tl & 1][w8row * 64];
#pragma unroll
    for (int rr = 0; rr < 128; rr += 32)
      g2l16(g + (size_t)rr * K, l + rr * 64);
  };

  const int cswl = (quad ^ (ln & 7)) * 8;
  const int aBase = (wm * (BM / 2) + ln) * 64;
  const int bBase = (wn * 64 + ln) * 64;

  f32x4 acc[MF][4];
#pragma unroll
  for (int i = 0; i < MF; i++)
#pragma unroll
    for (int j = 0; j < 4; j++) acc[i][j] = (f32x4){0.f, 0.f, 0.f, 0.f};

  bf16x8 af[MF][2], bfr[4][2];

  auto ldA = [&](int buf) {
#pragma unroll
    for (int mf = 0; mf < MF; ++mf)
#pragma unroll
      for (int sk = 0; sk < 2; ++sk)
        af[mf][sk] = *(const bf16x8*)&Ab[buf][aBase + mf * 1024 +
                                             (cswl ^ (sk << 5))];
  };
  auto ldB = [&](int buf) {
#pragma unroll
    for (int nf = 0; nf < 4; ++nf)
#pragma unroll
      for (int sk = 0; sk < 2; ++sk)
        bfr[nf][sk] = *(const bf16x8*)&Bb[buf][bBase + nf * 1024 +
                                               (cswl ^ (sk << 5))];
  };
  auto mm = [&]() {
#pragma unroll
    for (int mf = 0; mf < MF; ++mf)
#pragma unroll
      for (int nf = 0; nf < 4; ++nf) {
        f32x4 c = acc[mf][nf];
        c = MFMA16(af[mf][0], bfr[nf][0], c);
        c = MFMA16(af[mf][1], bfr[nf][1], c);
        acc[mf][nf] = c;
      }
  };

  stA(0); stB(0);
  __syncthreads();

  for (int tl = 0; tl < nt; ++tl) {
    const int buf = tl & 1;
    if (tl + 1 < nt) { stA(tl + 1); stB(tl + 1); }
    ldA(buf);
    ldB(buf);
    mm();
    __syncthreads();
  }

#pragma unroll
  for (int nf = 0; nf < 4; ++nf) {
    const int col = n0 + wn * 64 + nf * 16 + ln;
    const float bv = bias[col];
#pragma unroll
    for (int mf = 0; mf < MF; ++mf) {
      const int row = m0 + wm * (BM / 2) + mf * 16 + quad * 4;
#pragma unroll
      for (int r = 0; r < 4; ++r)
        C[(size_t)(row + r) * N + col] = (TC)(acc[mf][nf][r] + bv);
    }
  }
}

// ---------------------------------------------------------------------------
// Causal attention, K-SPLIT 8-WAVE (R9, kept): paired q-tiles (p,31-p), 512
// blocks, 512 threads. Wave w = (q-group w&3, k-half w>>2). Same aggregate
// work as the 4-wave version (128 MFMA/tile, same LDS traffic) but 2x waves
// -> 4 waves/SIMD and per-wave serial chains halved (TLP fix for the R2-
// measured latency-boundness; R4's unpair failed because it DOUBLED LDS
// work — this doesn't). Staging by role: waves 0-3 stage V, waves 4-7 stage
// K, with the verified 256-thread maps on t&255. Epilogue: cross-half O/l
// reduction through the dead K/V LDS buffers. R3 XCD map (bh low 5 bits),
// R6 f32x4 l-chains kept. GRID MUST BE 512.
// ---------------------------------------------------------------------------
__launch_bounds__(512, 4)
__global__ void attn_kernel(const bf16_t* __restrict__ qkv,
                            bf16_t* __restrict__ out) {
  constexpr int KP = 72, VP = 72;
  constexpr int BUF = 64 * KP;  // elems per K (or V) buffer
  __shared__ __align__(16) bf16_t KsB[2 * BUF];  // [buf][k][d], swizzled
  __shared__ __align__(16) bf16_t VtB[2 * BUF];  // [buf][d][k], swizzled

  const int t = threadIdx.x;
  const int wave = t >> 6, lane = t & 63, quad = lane >> 4, ln = lane & 15;
  const int qw = wave & 3;   // q-row group (16 rows)
  const int kh = wave >> 2;  // k-half of each 64-row tile
  const int p = blockIdx.x >> 5;   // pair: q-tiles p and 31-p (0..15)
  const int bh = blockIdx.x & 31;  // same-bh -> same XCD (mod-8)
  const int b = bh >> 4, h = bh & 15;
  const int qA = p * 64, qB = (31 - p) * 64;
  const int ntiles = 32 - p;       // A active for kt <= p; B for all
  const size_t rs = 3072;
  const size_t base = (size_t)b * 2048 * rs;

  // Q as B-operand frags: B[d=quad*8+j][q=ln] = Q[q][d]  (dup across kh)
  const size_t qoffA = base + (size_t)(qA + qw * 16 + ln) * rs + h * 64;
  const size_t qoffB = base + (size_t)(qB + qw * 16 + ln) * rs + h * 64;
  bf16x8 qfA0 = *(const bf16x8*)&qkv[qoffA + quad * 8];
  bf16x8 qfA1 = *(const bf16x8*)&qkv[qoffA + 32 + quad * 8];
  bf16x8 qfB0 = *(const bf16x8*)&qkv[qoffB + quad * 8];
  bf16x8 qfB1 = *(const bf16x8*)&qkv[qoffB + 32 + quad * 8];

  // O^T accumulators (per k-half partial): rows d = ct*16+quad*4+r, col q=ln
  f32x4 oA[4], oB[4];
  f32x4 lAv = (f32x4){0.f, 0.f, 0.f, 0.f};
  f32x4 lBv = (f32x4){0.f, 0.f, 0.f, 0.f};
  for (int ct = 0; ct < 4; ct++) {
    oA[ct] = (f32x4){0.f, 0.f, 0.f, 0.f};
    oB[ct] = (f32x4){0.f, 0.f, 0.f, 0.f};
  }

  // staging: role split. kh=0 waves stage V, kh=1 waves stage K, each using
  // the verified 256-thread maps on t256 = t & 255.
  const int t256 = t & 255;
  const int r0 = t256 >> 3, c0 = (t256 & 7) * 8;
  const int wav4 = t256 >> 6;  // == r0>>3
  const int ksA = r0 * KP + (((t256 & 7) + wav4) & 7) * 8;
  const int ksB2 = (r0 + 32) * KP + (((t256 & 7) + wav4 + 4) & 7) * 8;
  const int vkoff = ((((r0 >> 2) + (t256 & 7)) & 7)) * 8 + 2 * (r0 & 3);

  const bf16_t* gp0;
  const bf16_t* gp1;
  if (kh) {  // K stager: rows r0, r0+32
    gp0 = &qkv[base + 1024 + h * 64 + (size_t)r0 * rs + c0];
    gp1 = gp0 + (size_t)32 * rs;
  } else {   // V stager: rows 2*r0, 2*r0+1
    gp0 = &qkv[base + 2048 + h * 64 + (size_t)(2 * r0) * rs + c0];
    gp1 = gp0 + rs;
  }
  const size_t tstep = (size_t)64 * rs;

  // tile 0 into regs (role-shared register pair)
  bf16x8 s0 = *(const bf16x8*)gp0; gp0 += tstep;
  bf16x8 s1 = *(const bf16x8*)gp1; gp1 += tstep;

  const int qgA = qA + qw * 16 + ln;  // lane's q (S^T column), set A
  const int qgB = qB + qw * 16 + ln;

  auto stage_to = [&](int buf) {
    if (kh) {
      bf16_t* KsW = &KsB[buf * BUF];
      *(bf16x8*)&KsW[ksA] = s0;
      *(bf16x8*)&KsW[ksB2] = s1;
    } else {
      bf16_t* VtW = &VtB[buf * BUF];
#pragma unroll
      for (int j = 0; j < 8; j++) {
        bf16x2 w2 = {s0[j], s1[j]};
        *(bf16x2*)&VtW[(c0 + j) * VP + vkoff] = w2;
      }
    }
  };
  auto prefetch = [&]() {
    s0 = *(const bf16x8*)gp0; gp0 += tstep;
    s1 = *(const bf16x8*)gp1; gp1 += tstep;
  };
  auto load_kfs = [&](const bf16_t* Ks, bf16x8* kf0s, bf16x8* kf1s) {
#pragma unroll
    for (int sh = 0; sh < 2; sh++) {
      const int st = kh * 2 + sh;
      const int krow = st * 16 + ln;
      const int rot = 2 * st + (ln >> 3);
      kf0s[sh] = *(const bf16x8*)&Ks[krow * KP + ((quad + rot) & 7) * 8];
      kf1s[sh] = *(const bf16x8*)&Ks[krow * KP + ((quad + 4 + rot) & 7) * 8];
    }
  };
  auto qk_block = [&](const bf16x8* kf0s, const bf16x8* kf1s, bf16x8 q0,
                      bf16x8 q1, f32x4& lxv, bf16x8& Bp, bool masked,
                      int kbase, int qg) {
    u32x4 u;
#pragma unroll
    for (int sh = 0; sh < 2; sh++) {
      f32x4 s = (f32x4){0.f, 0.f, 0.f, 0.f};
      __builtin_amdgcn_s_setprio(1);
      s = MFMA16(kf0s[sh], q0, s);
      s = MFMA16(kf1s[sh], q1, s);
      __builtin_amdgcn_s_setprio(0);
      const int k0g = kbase + (kh * 2 + sh) * 16 + quad * 4;
      float pv[4];
#pragma unroll
      for (int r = 0; r < 4; r++) {
        float e = __builtin_amdgcn_exp2f(fmaf(s[r], SCALE_L2E, ROUND_B));
        if (masked && (k0g + r > qg)) e = 0.f;
        lxv[r] += e;
        pv[r] = e;
      }
      u[sh * 2] = pack2(pv[0], pv[1]);
      u[sh * 2 + 1] = pack2(pv[2], pv[3]);
    }
    Bp = __builtin_bit_cast(bf16x8, u);
  };
  auto load_vfs = [&](const bf16_t* Vt, bf16x8* A8s) {
#pragma unroll
    for (int ct = 0; ct < 4; ct++) {
      const int dd = ct * 16 + ln;
      const int bc = (quad >> 1) + 2 * ct + (ln >> 3);
      const int cA = (4 * kh + bc) & 7;
      const int cB = (4 * kh + 2 + bc) & 7;
      bf16x4 v0 = *(const bf16x4*)&Vt[dd * VP + cA * 8 + (quad & 1) * 4];
      bf16x4 v1 = *(const bf16x4*)&Vt[dd * VP + cB * 8 + (quad & 1) * 4];
      A8s[ct] = __builtin_shufflevector(v0, v1, 0, 1, 2, 3, 4, 5, 6, 7);
    }
  };

  // main body for one k-tile. hasA/maskA/maskB are literals at call sites.
  auto body = [&](int kt, bool hasA, bool maskA, bool maskB) {
    if (kt + 1 < ntiles) {
      stage_to((kt + 1) & 1);
      if (kt + 2 < ntiles) prefetch();
    }
    const bf16_t* Ks = &KsB[(kt & 1) * BUF];
    const bf16_t* Vt = &VtB[(kt & 1) * BUF];
    bf16x8 kf0s[2], kf1s[2];
    load_kfs(Ks, kf0s, kf1s);
    bf16x8 BpA, BpB;
    if (hasA) qk_block(kf0s, kf1s, qfA0, qfA1, lAv, BpA, maskA, kt * 64, qgA);
    qk_block(kf0s, kf1s, qfB0, qfB1, lBv, BpB, maskB, kt * 64, qgB);
    bf16x8 A8s[4];
    load_vfs(Vt, A8s);
    __builtin_amdgcn_s_setprio(1);
#pragma unroll
    for (int ct = 0; ct < 4; ct++) {
      if (hasA) oA[ct] = MFMA16(A8s[ct], BpA, oA[ct]);
      oB[ct] = MFMA16(A8s[ct], BpB, oB[ct]);
    }
    __builtin_amdgcn_s_setprio(0);
    if (kt + 1 < ntiles) __syncthreads();
  };

  // prologue: tile 0 into buf0, prefetch tile 1, sync
  stage_to(0);
  if (ntiles > 1) prefetch();
  __syncthreads();

  // peeled phases: [0,p) AB | p A-diag | (p,31-p) B-only | 31-p B-diag
  for (int kt = 0; kt < p; kt++) body(kt, true, false, false);
  body(p, true, true, false);
  for (int kt = p + 1; kt < 31 - p; kt++) body(kt, false, false, false);
  body(31 - p, false, false, true);

  // per-wave l: fold f32x4 chains, sum across the 4 quads (k within half)
  float lAx = (lAv[0] + lAv[1]) + (lAv[2] + lAv[3]);
  float lBx = (lBv[0] + lBv[1]) + (lBv[2] + lBv[3]);
  lAx += __shfl_xor(lAx, 16);
  lAx += __shfl_xor(lAx, 32);
  lBx += __shfl_xor(lBx, 16);
  lBx += __shfl_xor(lBx, 32);

  // cross-half reduction via dead K/V LDS. Scratch: 4 ct x 256 idx f32x4
  // (16384 B) + 256 f32 l (1024 B) per buffer; KsB/VtB are 18432 B each.
  __syncthreads();  // all tile reads complete before LDS reuse
  float* redA = (float*)KsB;
  float* redB = (float*)VtB;
  const int idx = qw * 64 + lane;  // partner wave (qw, kh^1) has same idx
  if (kh) {
#pragma unroll
    for (int ct = 0; ct < 4; ct++) {
      *(f32x4*)&redA[(ct * 256 + idx) * 4] = oA[ct];
      *(f32x4*)&redB[(ct * 256 + idx) * 4] = oB[ct];
    }
    redA[4096 + idx] = lAx;
    redB[4096 + idx] = lBx;
  }
  __syncthreads();
  if (!kh) {
#pragma unroll
    for (int ct = 0; ct < 4; ct++) {
      oA[ct] += *(const f32x4*)&redA[(ct * 256 + idx) * 4];
      oB[ct] += *(const f32x4*)&redB[(ct * 256 + idx) * 4];
    }
    lAx += redA[4096 + idx];
    lBx += redB[4096 + idx];
    const float invA = __builtin_amdgcn_rcpf(lAx);
    const float invB = __builtin_amdgcn_rcpf(lBx);
    const int ocol = h * 64 + quad * 4;
#pragma unroll
    for (int ct = 0; ct < 4; ct++) {
      bf16x4 wa, wb;
#pragma unroll
      for (int r = 0; r < 4; r++) {
        wa[r] = (bf16_t)(oA[ct][r] * invA);
        wb[r] = (bf16_t)(oB[ct][r] * invB);
      }
      *(bf16x4*)&out[(size_t)(b * 2048 + qgA) * 1024 + ocol + ct * 16] = wa;
      *(bf16x4*)&out[(size_t)(b * 2048 + qgB) * 1024 + ocol + ct * 16] = wb;
    }
  }
}

extern "C" void kernel_launch(void* const* d_in, const int* in_sizes, int n_in,
                              void* d_out, int out_size, void* d_ws, size_t ws_size,
                              hipStream_t stream) {
  const float* x     = (const float*)d_in[0];  // [2,2048,1024]
  const float* w_qkv = (const float*)d_in[1];  // [3072,1024]
  const float* b_qkv = (const float*)d_in[2];  // [3072]
  const float* w_o   = (const float*)d_in[3];  // [1024,1024]
  const float* b_o   = (const float*)d_in[4];  // [1024]
  float* out = (float*)d_out;                  // [2,2048,1024]

  // workspace (bf16): qkv | xbf/attn (aliased) | wqkv_bf | wo_bf  = 42 MB
  bf16_t* qkv   = (bf16_t*)d_ws;
  bf16_t* xbf   = qkv + (size_t)4096 * 3072;
  bf16_t* wqkvb = xbf + (size_t)4096 * 1024;
  bf16_t* wob   = wqkvb + (size_t)3072 * 1024;
  bf16_t* attn  = xbf;  // x dead after GEMM1

  const int na = 4096 * 1024, nb = 3072 * 1024, nc = 1024 * 1024;
  convert3_f32_bf16<<<dim3((na + nb + nc) / (256 * 8)), 256, 0, stream>>>(
      x, na, w_qkv, nb, w_o, nc, xbf, wqkvb, wob);

  // 1) qkv = x @ w_qkv^T + b_qkv   (128^2 BK=32 dbuf 1-barrier, 768 blocks,
  //    4-5 blocks/CU co-resident)
  gemm128k32<<<dim3(3072 / 128, 4096 / 128), 256, 0, stream>>>(
      xbf, wqkvb, b_qkv, qkv, 4096, 3072, 1024);
  // 2) causal attention, paired q-tiles, k-split 8-wave: EXACTLY 512 blocks
  attn_kernel<<<dim3(512), 512, 0, stream>>>(qkv, attn);
  // 3) out = attn @ w_o^T + b_o    (64x128 dbuf 1-barrier, 512 blocks, 2/CU)
  gemm128db<64, float><<<dim3(1024 / 128, 4096 / 64), 256, 0, stream>>>(
      attn, wob, b_o, out, 4096, 1024, 1024);
}